// Round 2
// baseline (327.011 us; speedup 1.0000x reference)
//
#include <hip/hip_runtime.h>
#include <hip/hip_bf16.h>

#define N_B     64
#define C_IN    9
#define T0      4096
#define C1      16
#define T1      2048
#define C2      32
#define T2      1024
#define N_NODES 65536
#define N_EDGES 524288
#define HID     128
#define OUT_C   10

// ---------------- CSR build ----------------

__global__ __launch_bounds__(256) void init_kernel(int* __restrict__ deg, float* __restrict__ pooled)
{
  int i = blockIdx.x * 256 + threadIdx.x;
  if (i < N_NODES) deg[i] = 0;
  if (i < N_B * HID) pooled[i] = 0.f;
}

__global__ __launch_bounds__(256) void count_kernel(const int* __restrict__ ei, int* __restrict__ deg)
{
  int e = blockIdx.x * 256 + threadIdx.x;
  if (e < N_EDGES) atomicAdd(&deg[ei[N_EDGES + e]], 1);
}

__global__ __launch_bounds__(256) void dinv_kernel(const int* __restrict__ deg, float* __restrict__ dinv)
{
  int i = blockIdx.x * 256 + threadIdx.x;
  if (i < N_NODES) dinv[i] = rsqrtf((float)deg[i] + 1.0f);  // +1 self loop
}

__global__ __launch_bounds__(256) void scanA_kernel(const int* __restrict__ deg, int* __restrict__ bsum)
{
  __shared__ int sd[256];
  int i = blockIdx.x * 256 + threadIdx.x;
  sd[threadIdx.x] = deg[i];
  __syncthreads();
  for (int d = 128; d > 0; d >>= 1) {
    if (threadIdx.x < d) sd[threadIdx.x] += sd[threadIdx.x + d];
    __syncthreads();
  }
  if (threadIdx.x == 0) bsum[blockIdx.x] = sd[0];
}

__global__ __launch_bounds__(256) void scanB_kernel(int* __restrict__ bsum)
{
  __shared__ int s[256];
  int tid = threadIdx.x;
  int v = bsum[tid];
  s[tid] = v;
  __syncthreads();
  for (int d = 1; d < 256; d <<= 1) {
    int add = (tid >= d) ? s[tid - d] : 0;
    __syncthreads();
    s[tid] += add;
    __syncthreads();
  }
  bsum[tid] = s[tid] - v;  // exclusive
}

__global__ __launch_bounds__(256) void scanC_kernel(const int* __restrict__ deg, const int* __restrict__ bsum,
                                                    int* __restrict__ off, int* __restrict__ cursor)
{
  __shared__ int s[256];
  int tid = threadIdx.x;
  int i = blockIdx.x * 256 + tid;
  int v = deg[i];
  s[tid] = v;
  __syncthreads();
  for (int d = 1; d < 256; d <<= 1) {
    int add = (tid >= d) ? s[tid - d] : 0;
    __syncthreads();
    s[tid] += add;
    __syncthreads();
  }
  int excl = s[tid] - v + bsum[blockIdx.x];
  off[i] = excl;
  cursor[i] = excl;
  if (i == N_NODES - 1) off[N_NODES] = excl + v;
}

__global__ __launch_bounds__(256) void scatter_kernel(const int* __restrict__ ei, int* __restrict__ cursor,
                                                      int* __restrict__ csr)
{
  int e = blockIdx.x * 256 + threadIdx.x;
  if (e < N_EDGES) {
    int d = ei[N_EDGES + e];
    int p = atomicAdd(&cursor[d], 1);
    csr[p] = ei[e];  // src
  }
}

// ---------------- conv stages (fused conv+relu+pool) ----------------

// grid 8192 = 64 b * 128 tiles, block 256 = 16 o * 16 p
__global__ __launch_bounds__(256) void conv1_kernel(const float* __restrict__ x, const float* __restrict__ w,
                                                    const float* __restrict__ bias, float* __restrict__ y1)
{
  __shared__ float swt[C_IN * 5 * C1];   // [c*5+k][o]
  __shared__ float sb[C1];
  __shared__ float sx[C_IN][36];
  int tid = threadIdx.x;
  int b = blockIdx.x >> 7;
  int p0 = (blockIdx.x & 127) << 4;
  for (int i = tid; i < C1 * C_IN * 5; i += 256) {
    int o = i / 45, r = i % 45;
    swt[r * C1 + o] = w[i];
  }
  if (tid < C1) sb[tid] = bias[tid];
  for (int i = tid; i < C_IN * 36; i += 256) {
    int c = i / 36, jj = i % 36;
    int t = 2 * p0 - 2 + jj;
    sx[c][jj] = (t >= 0 && t < T0) ? x[(b * C_IN + c) * T0 + t] : 0.f;
  }
  __syncthreads();
  int o = tid >> 4, pl = tid & 15;
  float acc0 = sb[o], acc1 = acc0;
  #pragma unroll
  for (int c = 0; c < C_IN; ++c) {
    float v0 = sx[c][2*pl], v1 = sx[c][2*pl+1], v2 = sx[c][2*pl+2],
          v3 = sx[c][2*pl+3], v4 = sx[c][2*pl+4], v5 = sx[c][2*pl+5];
    const float* wr = &swt[(c * 5) * C1 + o];
    float w0 = wr[0], w1 = wr[C1], w2 = wr[2*C1], w3 = wr[3*C1], w4 = wr[4*C1];
    acc0 += v0*w0 + v1*w1 + v2*w2 + v3*w3 + v4*w4;
    acc1 += v1*w0 + v2*w1 + v3*w2 + v4*w3 + v5*w4;
  }
  y1[(b * C1 + o) * T1 + p0 + pl] = fmaxf(fmaxf(acc0, acc1), 0.f);
}

// grid 8192 = 64 b * 128 tiles, block 256 = 8 p * 32 o; writes node-major [node][32]
__global__ __launch_bounds__(256) void conv2_kernel(const float* __restrict__ y1, const float* __restrict__ w,
                                                    const float* __restrict__ bias, float* __restrict__ feats)
{
  __shared__ float swt[C1 * 5 * C2];   // [c*5+k][o]
  __shared__ float sb[C2];
  __shared__ float sx[C1][20];
  int tid = threadIdx.x;
  int b = blockIdx.x >> 7;
  int p0 = (blockIdx.x & 127) << 3;
  for (int i = tid; i < C2 * C1 * 5; i += 256) {
    int o = i / 80, r = i % 80;
    swt[r * C2 + o] = w[i];
  }
  if (tid < C2) sb[tid] = bias[tid];
  for (int i = tid; i < C1 * 20; i += 256) {
    int c = i / 20, jj = i % 20;
    int t = 2 * p0 - 2 + jj;
    sx[c][jj] = (t >= 0 && t < T1) ? y1[(b * C1 + c) * T1 + t] : 0.f;
  }
  __syncthreads();
  int o = tid & 31, pl = tid >> 5;
  float acc0 = sb[o], acc1 = acc0;
  #pragma unroll
  for (int c = 0; c < C1; ++c) {
    float v0 = sx[c][2*pl], v1 = sx[c][2*pl+1], v2 = sx[c][2*pl+2],
          v3 = sx[c][2*pl+3], v4 = sx[c][2*pl+4], v5 = sx[c][2*pl+5];
    const float* wr = &swt[(c * 5) * C2 + o];
    float w0 = wr[0], w1 = wr[C2], w2 = wr[2*C2], w3 = wr[3*C2], w4 = wr[4*C2];
    acc0 += v0*w0 + v1*w1 + v2*w2 + v3*w3 + v4*w4;
    acc1 += v1*w0 + v2*w1 + v3*w2 + v4*w3 + v5*w4;
  }
  feats[((size_t)(b * T2) + p0 + pl) * C2 + o] = fmaxf(fmaxf(acc0, acc1), 0.f);
}

// ---------------- GCN dense GEMM: [nodes,K] @ [K,128] -> [nodes,128] ----------------
// block 256 = 8 node-groups x 32 j-groups, each thread 4 nodes x 4 j; 32 nodes/block
template<int K>
__global__ __launch_bounds__(256) void gemm_kernel(const float* __restrict__ A, const float* __restrict__ W,
                                                   float* __restrict__ C)
{
  __shared__ float sA[32 * K];
  int tid = threadIdx.x;
  int n0 = blockIdx.x << 5;
  for (int i = tid; i < 32 * K / 4; i += 256)
    ((float4*)sA)[i] = ((const float4*)(A + (size_t)n0 * K))[i];
  __syncthreads();
  int nq = (tid >> 5) << 2;
  int jq = (tid & 31) << 2;
  float acc[4][4] = {};
  #pragma unroll 4
  for (int i4 = 0; i4 < K / 4; ++i4) {
    float wv[4][4];
    #pragma unroll
    for (int ii = 0; ii < 4; ++ii) {
      float4 u = *(const float4*)(&W[(size_t)(i4 * 4 + ii) * HID + jq]);
      wv[ii][0] = u.x; wv[ii][1] = u.y; wv[ii][2] = u.z; wv[ii][3] = u.w;
    }
    #pragma unroll
    for (int nn = 0; nn < 4; ++nn) {
      float4 g = *(const float4*)&sA[(nq + nn) * K + (i4 << 2)];
      #pragma unroll
      for (int jj = 0; jj < 4; ++jj)
        acc[nn][jj] += g.x * wv[0][jj] + g.y * wv[1][jj] + g.z * wv[2][jj] + g.w * wv[3][jj];
    }
  }
  #pragma unroll
  for (int nn = 0; nn < 4; ++nn) {
    float4 o4 = make_float4(acc[nn][0], acc[nn][1], acc[nn][2], acc[nn][3]);
    *(float4*)&C[((size_t)(n0 + nq + nn)) * HID + jq] = o4;
  }
}

// ---------------- GCN aggregation: G[dst] = relu(sum_src H[src]*coef + H[dst]*dinv^2 + b) ----------------
// block 256 = 2 nodes x 128 j, grid N_NODES/2
__global__ __launch_bounds__(256) void agg_kernel(const float* __restrict__ H, const int* __restrict__ off,
                                                  const int* __restrict__ csr, const float* __restrict__ dinv,
                                                  const float* __restrict__ bias, float* __restrict__ G)
{
  int node = (blockIdx.x << 1) + (threadIdx.x >> 7);
  int j = threadIdx.x & 127;
  float dn = dinv[node];
  float acc = H[(size_t)node * HID + j] * dn * dn;
  int e0 = off[node], e1 = off[node + 1];
  int e = e0;
  for (; e + 4 <= e1; e += 4) {
    int s0 = csr[e], s1 = csr[e + 1], s2 = csr[e + 2], s3 = csr[e + 3];
    float c0 = dinv[s0] * dn, c1 = dinv[s1] * dn, c2 = dinv[s2] * dn, c3 = dinv[s3] * dn;
    float h0 = H[(size_t)s0 * HID + j], h1 = H[(size_t)s1 * HID + j];
    float h2 = H[(size_t)s2 * HID + j], h3 = H[(size_t)s3 * HID + j];
    acc += h0 * c0 + h1 * c1 + h2 * c2 + h3 * c3;
  }
  for (; e < e1; ++e) {
    int s = csr[e];
    acc += H[(size_t)s * HID + j] * (dinv[s] * dn);
  }
  acc += bias[j];
  G[(size_t)node * HID + j] = fmaxf(acc, 0.f);
}

// ---------------- mean pool + classifier ----------------

__global__ __launch_bounds__(128) void pool_kernel(const float* __restrict__ G, float* __restrict__ pooled)
{
  int b = blockIdx.x >> 3, chunk = blockIdx.x & 7;
  int j = threadIdx.x;
  float acc = 0.f;
  int t0 = chunk << 7;
  for (int t = t0; t < t0 + 128; ++t)
    acc += G[((size_t)(b << 10) + t) * HID + j];
  atomicAdd(&pooled[b * HID + j], acc * (1.0f / 1024.0f));
}

__global__ __launch_bounds__(64) void cls_kernel(const float* __restrict__ pooled, const float* __restrict__ w,
                                                 const float* __restrict__ cb, float* __restrict__ out)
{
  int b = blockIdx.x, o = threadIdx.x;
  if (o < OUT_C) {
    float acc = cb[o];
    for (int i = 0; i < HID; ++i)
      acc += pooled[b * HID + i] * w[i * OUT_C + o];
    out[b * OUT_C + o] = acc;
  }
}

// ---------------- launcher ----------------

extern "C" void kernel_launch(void* const* d_in, const int* in_sizes, int n_in,
                              void* d_out, int out_size, void* d_ws, size_t ws_size,
                              hipStream_t stream)
{
  const float* x    = (const float*)d_in[0];
  const int*   ei   = (const int*)d_in[1];
  const float* c1w  = (const float*)d_in[2];
  const float* c1b  = (const float*)d_in[3];
  const float* c2w  = (const float*)d_in[4];
  const float* c2b  = (const float*)d_in[5];
  const float* g1w  = (const float*)d_in[6];
  const float* g1b  = (const float*)d_in[7];
  const float* g2w  = (const float*)d_in[8];
  const float* g2b  = (const float*)d_in[9];
  const float* clsw = (const float*)d_in[10];
  const float* clsb = (const float*)d_in[11];
  float* outp = (float*)d_out;

  char* ws = (char*)d_ws;
  size_t off_b = 0;
  auto alloc = [&](size_t bytes) { void* p = ws + off_b; off_b = (off_b + bytes + 255) & ~(size_t)255; return p; };
  int*   deg    = (int*)  alloc((size_t)N_NODES * 4);
  float* dinvv  = (float*)alloc((size_t)N_NODES * 4);
  int*   offp   = (int*)  alloc((size_t)(N_NODES + 1) * 4);
  int*   cursor = (int*)  alloc((size_t)N_NODES * 4);
  int*   bsum   = (int*)  alloc(256 * 4);
  int*   csr    = (int*)  alloc((size_t)N_EDGES * 4);
  float* y1     = (float*)alloc((size_t)N_B * C1 * T1 * 4);
  float* feats  = (float*)alloc((size_t)N_NODES * C2 * 4);
  float* H      = (float*)alloc((size_t)N_NODES * HID * 4);
  float* G      = (float*)alloc((size_t)N_NODES * HID * 4);
  float* pooled = (float*)alloc((size_t)N_B * HID * 4);
  (void)ws_size; (void)in_sizes; (void)n_in; (void)out_size;

  // CSR build
  init_kernel   <<<256, 256, 0, stream>>>(deg, pooled);
  count_kernel  <<<N_EDGES / 256, 256, 0, stream>>>(ei, deg);
  dinv_kernel   <<<N_NODES / 256, 256, 0, stream>>>(deg, dinvv);
  scanA_kernel  <<<256, 256, 0, stream>>>(deg, bsum);
  scanB_kernel  <<<1, 256, 0, stream>>>(bsum);
  scanC_kernel  <<<256, 256, 0, stream>>>(deg, bsum, offp, cursor);
  scatter_kernel<<<N_EDGES / 256, 256, 0, stream>>>(ei, cursor, csr);

  // CNN feature extractor
  conv1_kernel<<<8192, 256, 0, stream>>>(x, c1w, c1b, y1);
  conv2_kernel<<<8192, 256, 0, stream>>>(y1, c2w, c2b, feats);

  // GCN layer 1
  gemm_kernel<32> <<<N_NODES / 32, 256, 0, stream>>>(feats, g1w, H);
  agg_kernel      <<<N_NODES / 2, 256, 0, stream>>>(H, offp, csr, dinvv, g1b, G);
  // GCN layer 2
  gemm_kernel<128><<<N_NODES / 32, 256, 0, stream>>>(G, g2w, H);
  agg_kernel      <<<N_NODES / 2, 256, 0, stream>>>(H, offp, csr, dinvv, g2b, G);

  // pool + classifier
  pool_kernel<<<N_B * 8, 128, 0, stream>>>(G, pooled);
  cls_kernel <<<N_B, 64, 0, stream>>>(pooled, clsw, clsb, outp);
}

// Round 4
// 243.287 us; speedup vs baseline: 1.3441x; 1.3441x over previous
//
#include <hip/hip_runtime.h>
#include <hip/hip_bf16.h>

typedef __hip_bfloat16 bf16;
typedef unsigned short ushort8_v __attribute__((ext_vector_type(8)));

#define N_B     64
#define C_IN    9
#define T0      4096
#define C1      16
#define T1      2048
#define C2      32
#define T2      1024
#define N_NODES 65536
#define N_EDGES 524288
#define HID     128
#define OUT_C   10

__device__ __forceinline__ float us2f(unsigned short u) {
  union { unsigned int i; float f; } c; c.i = ((unsigned int)u) << 16; return c.f;
}
__device__ __forceinline__ unsigned short f2us(float f) {
  bf16 h = __float2bfloat16(f);
  unsigned short u;
  __builtin_memcpy(&u, &h, 2);
  return u;
}

// ---------------- CSR build ----------------

__global__ __launch_bounds__(256) void init_kernel(int* __restrict__ deg, float* __restrict__ pooled)
{
  int i = blockIdx.x * 256 + threadIdx.x;
  if (i < N_NODES) deg[i] = 0;
  if (i < N_B * HID) pooled[i] = 0.f;
}

__global__ __launch_bounds__(256) void count_kernel(const int* __restrict__ ei, int* __restrict__ deg)
{
  int e = blockIdx.x * 256 + threadIdx.x;
  if (e < N_EDGES) atomicAdd(&deg[ei[N_EDGES + e]], 1);
}

__global__ __launch_bounds__(256) void dinv_kernel(const int* __restrict__ deg, float* __restrict__ dinv)
{
  int i = blockIdx.x * 256 + threadIdx.x;
  if (i < N_NODES) dinv[i] = rsqrtf((float)deg[i] + 1.0f);  // +1 self loop
}

__global__ __launch_bounds__(256) void scanA_kernel(const int* __restrict__ deg, int* __restrict__ bsum)
{
  __shared__ int sd[256];
  int i = blockIdx.x * 256 + threadIdx.x;
  sd[threadIdx.x] = deg[i];
  __syncthreads();
  for (int d = 128; d > 0; d >>= 1) {
    if (threadIdx.x < d) sd[threadIdx.x] += sd[threadIdx.x + d];
    __syncthreads();
  }
  if (threadIdx.x == 0) bsum[blockIdx.x] = sd[0];
}

__global__ __launch_bounds__(256) void scanB_kernel(int* __restrict__ bsum)
{
  __shared__ int s[256];
  int tid = threadIdx.x;
  int v = bsum[tid];
  s[tid] = v;
  __syncthreads();
  for (int d = 1; d < 256; d <<= 1) {
    int add = (tid >= d) ? s[tid - d] : 0;
    __syncthreads();
    s[tid] += add;
    __syncthreads();
  }
  bsum[tid] = s[tid] - v;  // exclusive
}

__global__ __launch_bounds__(256) void scanC_kernel(const int* __restrict__ deg, const int* __restrict__ bsum,
                                                    int* __restrict__ off, int* __restrict__ cursor)
{
  __shared__ int s[256];
  int tid = threadIdx.x;
  int i = blockIdx.x * 256 + tid;
  int v = deg[i];
  s[tid] = v;
  __syncthreads();
  for (int d = 1; d < 256; d <<= 1) {
    int add = (tid >= d) ? s[tid - d] : 0;
    __syncthreads();
    s[tid] += add;
    __syncthreads();
  }
  int excl = s[tid] - v + bsum[blockIdx.x];
  off[i] = excl;
  cursor[i] = excl;
  if (i == N_NODES - 1) off[N_NODES] = excl + v;
}

// store src index AND precomputed coef = dinv[src]*dinv[dst] (linear reads in agg)
__global__ __launch_bounds__(256) void scatter_kernel(const int* __restrict__ ei, int* __restrict__ cursor,
                                                      const float* __restrict__ dinv,
                                                      int* __restrict__ csr, float* __restrict__ coef)
{
  int e = blockIdx.x * 256 + threadIdx.x;
  if (e < N_EDGES) {
    int d = ei[N_EDGES + e];
    int s = ei[e];
    int p = atomicAdd(&cursor[d], 1);
    csr[p] = s;
    coef[p] = dinv[s] * dinv[d];
  }
}

// ---------------- conv stages (fused conv+relu+pool) ----------------

// grid 8192 = 64 b * 128 tiles, block 256 = 16 o * 16 p
__global__ __launch_bounds__(256) void conv1_kernel(const float* __restrict__ x, const float* __restrict__ w,
                                                    const float* __restrict__ bias, float* __restrict__ y1)
{
  __shared__ float swt[C_IN * 5 * C1];   // [c*5+k][o]
  __shared__ float sb[C1];
  __shared__ float sx[C_IN][36];
  int tid = threadIdx.x;
  int b = blockIdx.x >> 7;
  int p0 = (blockIdx.x & 127) << 4;
  for (int i = tid; i < C1 * C_IN * 5; i += 256) {
    int o = i / 45, r = i % 45;
    swt[r * C1 + o] = w[i];
  }
  if (tid < C1) sb[tid] = bias[tid];
  for (int i = tid; i < C_IN * 36; i += 256) {
    int c = i / 36, jj = i % 36;
    int t = 2 * p0 - 2 + jj;
    sx[c][jj] = (t >= 0 && t < T0) ? x[(b * C_IN + c) * T0 + t] : 0.f;
  }
  __syncthreads();
  int o = tid >> 4, pl = tid & 15;
  float acc0 = sb[o], acc1 = acc0;
  #pragma unroll
  for (int c = 0; c < C_IN; ++c) {
    float v0 = sx[c][2*pl], v1 = sx[c][2*pl+1], v2 = sx[c][2*pl+2],
          v3 = sx[c][2*pl+3], v4 = sx[c][2*pl+4], v5 = sx[c][2*pl+5];
    const float* wr = &swt[(c * 5) * C1 + o];
    float w0 = wr[0], w1 = wr[C1], w2 = wr[2*C1], w3 = wr[3*C1], w4 = wr[4*C1];
    acc0 += v0*w0 + v1*w1 + v2*w2 + v3*w3 + v4*w4;
    acc1 += v1*w0 + v2*w1 + v3*w2 + v4*w3 + v5*w4;
  }
  y1[(b * C1 + o) * T1 + p0 + pl] = fmaxf(fmaxf(acc0, acc1), 0.f);
}

// grid 8192, block 256 = 8 p * 32 o; writes node-major bf16 [node][32]
__global__ __launch_bounds__(256) void conv2_kernel(const float* __restrict__ y1, const float* __restrict__ w,
                                                    const float* __restrict__ bias, unsigned short* __restrict__ feats)
{
  __shared__ float swt[C1 * 5 * C2];   // [c*5+k][o]
  __shared__ float sb[C2];
  __shared__ float sx[C1][20];
  int tid = threadIdx.x;
  int b = blockIdx.x >> 7;
  int p0 = (blockIdx.x & 127) << 3;
  for (int i = tid; i < C2 * C1 * 5; i += 256) {
    int o = i / 80, r = i % 80;
    swt[r * C2 + o] = w[i];
  }
  if (tid < C2) sb[tid] = bias[tid];
  for (int i = tid; i < C1 * 20; i += 256) {
    int c = i / 20, jj = i % 20;
    int t = 2 * p0 - 2 + jj;
    sx[c][jj] = (t >= 0 && t < T1) ? y1[(b * C1 + c) * T1 + t] : 0.f;
  }
  __syncthreads();
  int o = tid & 31, pl = tid >> 5;
  float acc0 = sb[o], acc1 = acc0;
  #pragma unroll
  for (int c = 0; c < C1; ++c) {
    float v0 = sx[c][2*pl], v1 = sx[c][2*pl+1], v2 = sx[c][2*pl+2],
          v3 = sx[c][2*pl+3], v4 = sx[c][2*pl+4], v5 = sx[c][2*pl+5];
    const float* wr = &swt[(c * 5) * C2 + o];
    float w0 = wr[0], w1 = wr[C2], w2 = wr[2*C2], w3 = wr[3*C2], w4 = wr[4*C2];
    acc0 += v0*w0 + v1*w1 + v2*w2 + v3*w3 + v4*w4;
    acc1 += v1*w0 + v2*w1 + v3*w2 + v4*w3 + v5*w4;
  }
  feats[((size_t)(b * T2) + p0 + pl) * C2 + o] = f2us(fmaxf(fmaxf(acc0, acc1), 0.f));
}

// ---------------- aggX: aggregate 32-dim bf16 feats -> fp32 [N,32] ----------------
// block 256 = 64 nodes x 4 lanes (8 bf16 each); grid 1024
__global__ __launch_bounds__(256) void aggX_kernel(const unsigned short* __restrict__ F, const int* __restrict__ off,
                                                   const int* __restrict__ csr, const float* __restrict__ coef,
                                                   const float* __restrict__ dinv, float* __restrict__ aggX)
{
  int tid = threadIdx.x;
  int node = (blockIdx.x << 6) + (tid >> 2);
  int jq = (tid & 3) << 3;                  // bf16 element offset
  float dn = dinv[node];
  float acc[8];
  {
    ushort8_v r = *(const ushort8_v*)(F + (size_t)node * C2 + jq);
    float c = dn * dn;
    #pragma unroll
    for (int k = 0; k < 8; ++k) acc[k] = us2f(r[k]) * c;
  }
  int e0 = off[node], e1 = off[node + 1];
  int e = e0;
  for (; e + 2 <= e1; e += 2) {
    int s0 = csr[e], s1 = csr[e + 1];
    float c0 = coef[e], c1 = coef[e + 1];
    ushort8_v r0 = *(const ushort8_v*)(F + (size_t)s0 * C2 + jq);
    ushort8_v r1 = *(const ushort8_v*)(F + (size_t)s1 * C2 + jq);
    #pragma unroll
    for (int k = 0; k < 8; ++k) acc[k] += us2f(r0[k]) * c0 + us2f(r1[k]) * c1;
  }
  if (e < e1) {
    int s0 = csr[e];
    float c0 = coef[e];
    ushort8_v r0 = *(const ushort8_v*)(F + (size_t)s0 * C2 + jq);
    #pragma unroll
    for (int k = 0; k < 8; ++k) acc[k] += us2f(r0[k]) * c0;
  }
  float* dst = aggX + (size_t)node * C2 + jq;
  *(float4*)(dst)     = make_float4(acc[0], acc[1], acc[2], acc[3]);
  *(float4*)(dst + 4) = make_float4(acc[4], acc[5], acc[6], acc[7]);
}

// ---------------- GEMM: [nodes,K] @ [K,128] -> [nodes,128] ----------------
// MODE 0: out fp32 with bias+relu.  MODE 1: out bf16 raw.
template<int K, int MODE>
__global__ __launch_bounds__(256) void gemm_kernel(const float* __restrict__ A, const float* __restrict__ W,
                                                   const float* __restrict__ bias,
                                                   float* __restrict__ Cf, unsigned short* __restrict__ Cb)
{
  __shared__ float sA[32 * K];
  int tid = threadIdx.x;
  int n0 = blockIdx.x << 5;
  for (int i = tid; i < 32 * K / 4; i += 256)
    ((float4*)sA)[i] = ((const float4*)(A + (size_t)n0 * K))[i];
  __syncthreads();
  int nq = (tid >> 5) << 2;
  int jq = (tid & 31) << 2;
  float acc[4][4] = {};
  #pragma unroll 4
  for (int i4 = 0; i4 < K / 4; ++i4) {
    float wv[4][4];
    #pragma unroll
    for (int ii = 0; ii < 4; ++ii) {
      float4 u = *(const float4*)(&W[(size_t)(i4 * 4 + ii) * HID + jq]);
      wv[ii][0] = u.x; wv[ii][1] = u.y; wv[ii][2] = u.z; wv[ii][3] = u.w;
    }
    #pragma unroll
    for (int nn = 0; nn < 4; ++nn) {
      float4 g = *(const float4*)&sA[(nq + nn) * K + (i4 << 2)];
      #pragma unroll
      for (int jj = 0; jj < 4; ++jj)
        acc[nn][jj] += g.x * wv[0][jj] + g.y * wv[1][jj] + g.z * wv[2][jj] + g.w * wv[3][jj];
    }
  }
  if (MODE == 0) {
    float b0 = bias[jq], b1 = bias[jq + 1], b2 = bias[jq + 2], b3 = bias[jq + 3];
    #pragma unroll
    for (int nn = 0; nn < 4; ++nn) {
      float4 o4 = make_float4(fmaxf(acc[nn][0] + b0, 0.f), fmaxf(acc[nn][1] + b1, 0.f),
                              fmaxf(acc[nn][2] + b2, 0.f), fmaxf(acc[nn][3] + b3, 0.f));
      *(float4*)&Cf[((size_t)(n0 + nq + nn)) * HID + jq] = o4;
    }
  } else {
    #pragma unroll
    for (int nn = 0; nn < 4; ++nn) {
      ushort4 u;
      u.x = f2us(acc[nn][0]);
      u.y = f2us(acc[nn][1]);
      u.z = f2us(acc[nn][2]);
      u.w = f2us(acc[nn][3]);
      *(ushort4*)(Cb + ((size_t)(n0 + nq + nn)) * HID + jq) = u;
    }
  }
}

// ---------------- agg2 + bias + relu + mean-pool (fused) ----------------
// block 256 = 16 nodes x 16 lanes (8 bf16 each); grid 4096; never materializes G2
__global__ __launch_bounds__(256) void agg2_pool_kernel(const unsigned short* __restrict__ Hb, const int* __restrict__ off,
                                                        const int* __restrict__ csr, const float* __restrict__ coef,
                                                        const float* __restrict__ dinv, const float* __restrict__ bias,
                                                        float* __restrict__ pooled)
{
  __shared__ float red[16][HID];           // 8 KB
  int tid = threadIdx.x;
  int g = tid >> 4;                        // local node 0..15
  int jq = (tid & 15) << 3;                // bf16 element offset 0..120
  int node = (blockIdx.x << 4) + g;
  float dn = dinv[node];
  float acc[8];
  {
    ushort8_v r = *(const ushort8_v*)(Hb + (size_t)node * HID + jq);
    float c = dn * dn;
    #pragma unroll
    for (int k = 0; k < 8; ++k) acc[k] = us2f(r[k]) * c;
  }
  int e0 = off[node], e1 = off[node + 1];
  int e = e0;
  for (; e + 2 <= e1; e += 2) {
    int s0 = csr[e], s1 = csr[e + 1];
    float c0 = coef[e], c1 = coef[e + 1];
    ushort8_v r0 = *(const ushort8_v*)(Hb + (size_t)s0 * HID + jq);
    ushort8_v r1 = *(const ushort8_v*)(Hb + (size_t)s1 * HID + jq);
    #pragma unroll
    for (int k = 0; k < 8; ++k) acc[k] += us2f(r0[k]) * c0 + us2f(r1[k]) * c1;
  }
  if (e < e1) {
    int s0 = csr[e];
    float c0 = coef[e];
    ushort8_v r0 = *(const ushort8_v*)(Hb + (size_t)s0 * HID + jq);
    #pragma unroll
    for (int k = 0; k < 8; ++k) acc[k] += us2f(r0[k]) * c0;
  }
  #pragma unroll
  for (int k = 0; k < 8; ++k)
    red[g][jq + k] = fmaxf(acc[k] + bias[jq + k], 0.f);
  __syncthreads();
  if (tid < HID) {
    float s = 0.f;
    #pragma unroll
    for (int g2 = 0; g2 < 16; ++g2) s += red[g2][tid];
    int b = blockIdx.x >> 6;               // 64 blocks per graph
    atomicAdd(&pooled[b * HID + tid], s * (1.0f / 1024.0f));
  }
}

// ---------------- classifier ----------------

__global__ __launch_bounds__(64) void cls_kernel(const float* __restrict__ pooled, const float* __restrict__ w,
                                                 const float* __restrict__ cb, float* __restrict__ out)
{
  int b = blockIdx.x, o = threadIdx.x;
  if (o < OUT_C) {
    float acc = cb[o];
    for (int i = 0; i < HID; ++i)
      acc += pooled[b * HID + i] * w[i * OUT_C + o];
    out[b * OUT_C + o] = acc;
  }
}

// ---------------- launcher ----------------

extern "C" void kernel_launch(void* const* d_in, const int* in_sizes, int n_in,
                              void* d_out, int out_size, void* d_ws, size_t ws_size,
                              hipStream_t stream)
{
  const float* x    = (const float*)d_in[0];
  const int*   ei   = (const int*)d_in[1];
  const float* c1w  = (const float*)d_in[2];
  const float* c1b  = (const float*)d_in[3];
  const float* c2w  = (const float*)d_in[4];
  const float* c2b  = (const float*)d_in[5];
  const float* g1w  = (const float*)d_in[6];
  const float* g1b  = (const float*)d_in[7];
  const float* g2w  = (const float*)d_in[8];
  const float* g2b  = (const float*)d_in[9];
  const float* clsw = (const float*)d_in[10];
  const float* clsb = (const float*)d_in[11];
  float* outp = (float*)d_out;

  char* ws = (char*)d_ws;
  size_t off_b = 0;
  auto alloc = [&](size_t bytes) { void* p = ws + off_b; off_b = (off_b + bytes + 255) & ~(size_t)255; return p; };
  int*   deg    = (int*)  alloc((size_t)N_NODES * 4);
  float* dinvv  = (float*)alloc((size_t)N_NODES * 4);
  int*   offp   = (int*)  alloc((size_t)(N_NODES + 1) * 4);
  int*   cursor = (int*)  alloc((size_t)N_NODES * 4);
  int*   bsum   = (int*)  alloc(256 * 4);
  int*   csr    = (int*)  alloc((size_t)N_EDGES * 4);
  float* coefp  = (float*)alloc((size_t)N_EDGES * 4);
  float* y1     = (float*)alloc((size_t)N_B * C1 * T1 * 4);
  unsigned short* feats = (unsigned short*)alloc((size_t)N_NODES * C2 * 2);
  float* aggX   = (float*)alloc((size_t)N_NODES * C2 * 4);
  float* G      = (float*)alloc((size_t)N_NODES * HID * 4);
  unsigned short* H = (unsigned short*)alloc((size_t)N_NODES * HID * 2);
  float* pooled = (float*)alloc((size_t)N_B * HID * 4);
  (void)ws_size; (void)in_sizes; (void)n_in; (void)out_size;

  // CSR build
  init_kernel   <<<256, 256, 0, stream>>>(deg, pooled);
  count_kernel  <<<N_EDGES / 256, 256, 0, stream>>>(ei, deg);
  dinv_kernel   <<<N_NODES / 256, 256, 0, stream>>>(deg, dinvv);
  scanA_kernel  <<<256, 256, 0, stream>>>(deg, bsum);
  scanB_kernel  <<<1, 256, 0, stream>>>(bsum);
  scanC_kernel  <<<256, 256, 0, stream>>>(deg, bsum, offp, cursor);
  scatter_kernel<<<N_EDGES / 256, 256, 0, stream>>>(ei, cursor, dinvv, csr, coefp);

  // CNN feature extractor
  conv1_kernel<<<8192, 256, 0, stream>>>(x, c1w, c1b, y1);
  conv2_kernel<<<8192, 256, 0, stream>>>(y1, c2w, c2b, feats);

  // GCN layer 1: (A X) W1 + b1, relu
  aggX_kernel<<<N_NODES / 64, 256, 0, stream>>>(feats, offp, csr, coefp, dinvv, aggX);
  gemm_kernel<32, 0><<<N_NODES / 32, 256, 0, stream>>>(aggX, g1w, g1b, G, nullptr);

  // GCN layer 2: A (G W2) + b2, relu, fused mean-pool
  gemm_kernel<128, 1><<<N_NODES / 32, 256, 0, stream>>>(G, g2w, nullptr, nullptr, H);
  agg2_pool_kernel<<<N_NODES / 16, 256, 0, stream>>>(H, offp, csr, coefp, dinvv, g2b, pooled);

  // classifier
  cls_kernel<<<N_B, 64, 0, stream>>>(pooled, clsw, clsb, outp);
}

// Round 5
// 215.587 us; speedup vs baseline: 1.5168x; 1.1285x over previous
//
#include <hip/hip_runtime.h>
#include <hip/hip_bf16.h>

typedef __hip_bfloat16 bf16;
typedef unsigned short ushort8_v __attribute__((ext_vector_type(8)));

#define N_B     64
#define C_IN    9
#define T0      4096
#define C1      16
#define T1      2048
#define C2      32
#define T2      1024
#define N_NODES 65536
#define N_EDGES 524288
#define HID     128
#define OUT_C   10

__device__ __forceinline__ float us2f(unsigned short u) {
  union { unsigned int i; float f; } c; c.i = ((unsigned int)u) << 16; return c.f;
}
__device__ __forceinline__ unsigned short f2us(float f) {
  bf16 h = __float2bfloat16(f);
  unsigned short u;
  __builtin_memcpy(&u, &h, 2);
  return u;
}

// ---------------- CSR build ----------------

__global__ __launch_bounds__(256) void init_kernel(int* __restrict__ deg, float* __restrict__ pooled)
{
  int i = blockIdx.x * 256 + threadIdx.x;
  if (i < N_NODES) deg[i] = 0;
  if (i < N_B * HID) pooled[i] = 0.f;
}

__global__ __launch_bounds__(256) void count_kernel(const int* __restrict__ ei, int* __restrict__ deg)
{
  int e = blockIdx.x * 256 + threadIdx.x;
  if (e < N_EDGES) atomicAdd(&deg[ei[N_EDGES + e]], 1);
}

__global__ __launch_bounds__(256) void dinv_kernel(const int* __restrict__ deg, float* __restrict__ dinv)
{
  int i = blockIdx.x * 256 + threadIdx.x;
  if (i < N_NODES) dinv[i] = rsqrtf((float)deg[i] + 1.0f);  // +1 self loop
}

__global__ __launch_bounds__(256) void scanA_kernel(const int* __restrict__ deg, int* __restrict__ bsum)
{
  __shared__ int sd[256];
  int i = blockIdx.x * 256 + threadIdx.x;
  sd[threadIdx.x] = deg[i];
  __syncthreads();
  for (int d = 128; d > 0; d >>= 1) {
    if (threadIdx.x < d) sd[threadIdx.x] += sd[threadIdx.x + d];
    __syncthreads();
  }
  if (threadIdx.x == 0) bsum[blockIdx.x] = sd[0];
}

__global__ __launch_bounds__(256) void scanB_kernel(int* __restrict__ bsum)
{
  __shared__ int s[256];
  int tid = threadIdx.x;
  int v = bsum[tid];
  s[tid] = v;
  __syncthreads();
  for (int d = 1; d < 256; d <<= 1) {
    int add = (tid >= d) ? s[tid - d] : 0;
    __syncthreads();
    s[tid] += add;
    __syncthreads();
  }
  bsum[tid] = s[tid] - v;  // exclusive
}

__global__ __launch_bounds__(256) void scanC_kernel(const int* __restrict__ deg, const int* __restrict__ bsum,
                                                    int* __restrict__ off, int* __restrict__ cursor)
{
  __shared__ int s[256];
  int tid = threadIdx.x;
  int i = blockIdx.x * 256 + tid;
  int v = deg[i];
  s[tid] = v;
  __syncthreads();
  for (int d = 1; d < 256; d <<= 1) {
    int add = (tid >= d) ? s[tid - d] : 0;
    __syncthreads();
    s[tid] += add;
    __syncthreads();
  }
  int excl = s[tid] - v + bsum[blockIdx.x];
  off[i] = excl;
  cursor[i] = excl;
  if (i == N_NODES - 1) off[N_NODES] = excl + v;
}

// store src index AND precomputed coef = dinv[src]*dinv[dst] (linear reads in agg)
__global__ __launch_bounds__(256) void scatter_kernel(const int* __restrict__ ei, int* __restrict__ cursor,
                                                      const float* __restrict__ dinv,
                                                      int* __restrict__ csr, float* __restrict__ coef)
{
  int e = blockIdx.x * 256 + threadIdx.x;
  if (e < N_EDGES) {
    int d = ei[N_EDGES + e];
    int s = ei[e];
    int p = atomicAdd(&cursor[d], 1);
    csr[p] = s;
    coef[p] = dinv[s] * dinv[d];
  }
}

// ---------------- fused conv1+relu+pool+conv2+relu+pool ----------------
// grid 1024 = 64 b * 16 tiles(64 final positions); block 256.
// LDS: x tile (flat, contiguous), weights [r][o] with ODD padded strides (17/33)
// so both staging writes and compute reads are bank-conflict-free; y1 tile stride 137.
__global__ __launch_bounds__(256) void conv_fused_kernel(const float* __restrict__ x,
                                                         const float* __restrict__ w1, const float* __restrict__ b1,
                                                         const float* __restrict__ w2, const float* __restrict__ b2,
                                                         unsigned short* __restrict__ feats)
{
  __shared__ float sx[C_IN * 272];    // 9.8 KB
  __shared__ float sw1[45 * 17];      // 3.1 KB  [r=c*5+k][o], stride 17
  __shared__ float sw2[80 * 33];      // 10.6 KB [r=c*5+k][o], stride 33
  __shared__ float sy[C1 * 137];      // 8.8 KB  [c][pp], stride 137
  __shared__ float sb1[C1], sb2[C2];
  int tid = threadIdx.x;
  int b = blockIdx.x >> 4;
  int q0 = (blockIdx.x & 15) << 6;    // final-output tile start (T2 coords)
  int x0 = 4 * q0 - 6;                // x tile start

  for (int i = tid; i < C1 * 45; i += 256) sw1[(i % 45) * 17 + i / 45] = w1[i];
  for (int i = tid; i < C2 * 80; i += 256) sw2[(i % 80) * 33 + i / 80] = w2[i];
  if (tid < C1) sb1[tid] = b1[tid];
  else if (tid >= 32 && tid < 32 + C2) sb2[tid - 32] = b2[tid - 32];
  for (int i = tid; i < C_IN * 272; i += 256) {
    int c = i / 272, t = i % 272;
    int tg = x0 + t;
    sx[i] = (tg >= 0 && tg < T0) ? x[(b * C_IN + c) * T0 + tg] : 0.f;
  }
  __syncthreads();

  // stage 1: y1 local pp -> global p = 2*q0-2+pp, pp in [0,132)
  {
    int o = tid & 15;
    float bias = sb1[o];
    for (int pp = tid >> 4; pp < 132; pp += 16) {
      int p = 2 * q0 - 2 + pp;
      float v = 0.f;
      if (p >= 0 && p < T1) {
        float a0 = bias, a1 = bias;
        #pragma unroll
        for (int c = 0; c < C_IN; ++c) {
          const float* xr = &sx[c * 272 + 2 * pp];
          const float* wr = &sw1[(c * 5) * 17 + o];
          float v0 = xr[0], v1 = xr[1], v2 = xr[2], v3 = xr[3], v4 = xr[4], v5 = xr[5];
          float w0 = wr[0], w1_ = wr[17], w2_ = wr[34], w3_ = wr[51], w4_ = wr[68];
          a0 += v0*w0 + v1*w1_ + v2*w2_ + v3*w3_ + v4*w4_;
          a1 += v1*w0 + v2*w1_ + v3*w2_ + v4*w3_ + v5*w4_;
        }
        v = fmaxf(fmaxf(a0, a1), 0.f);
      }
      sy[o * 137 + pp] = v;
    }
  }
  __syncthreads();

  // stage 2: 64 final positions x 32 channels, thread = (o, pos-group)
  {
    int o = tid & 31;
    int pg = tid >> 5;                  // 0..7
    float bias = sb2[o];
    #pragma unroll
    for (int i = 0; i < 8; ++i) {
      int qq = pg + (i << 3);           // 0..63
      float a0 = bias, a1 = bias;
      #pragma unroll
      for (int c = 0; c < C1; ++c) {
        const float* yr = &sy[c * 137 + 2 * qq];
        const float* wr = &sw2[(c * 5) * 33 + o];
        float v0 = yr[0], v1 = yr[1], v2 = yr[2], v3 = yr[3], v4 = yr[4], v5 = yr[5];
        float w0 = wr[0], w1_ = wr[33], w2_ = wr[66], w3_ = wr[99], w4_ = wr[132];
        a0 += v0*w0 + v1*w1_ + v2*w2_ + v3*w3_ + v4*w4_;
        a1 += v1*w0 + v2*w1_ + v3*w2_ + v4*w3_ + v5*w4_;
      }
      int node = (b << 10) + q0 + qq;
      feats[(size_t)node * C2 + o] = f2us(fmaxf(fmaxf(a0, a1), 0.f));
    }
  }
}

// ---------------- aggX: aggregate 32-dim bf16 feats -> fp32 [N,32] ----------------
// block 256 = 64 nodes x 4 lanes (8 bf16 each); grid 1024
__global__ __launch_bounds__(256) void aggX_kernel(const unsigned short* __restrict__ F, const int* __restrict__ off,
                                                   const int* __restrict__ csr, const float* __restrict__ coef,
                                                   const float* __restrict__ dinv, float* __restrict__ aggX)
{
  int tid = threadIdx.x;
  int node = (blockIdx.x << 6) + (tid >> 2);
  int jq = (tid & 3) << 3;                  // bf16 element offset
  float dn = dinv[node];
  float acc[8];
  {
    ushort8_v r = *(const ushort8_v*)(F + (size_t)node * C2 + jq);
    float c = dn * dn;
    #pragma unroll
    for (int k = 0; k < 8; ++k) acc[k] = us2f(r[k]) * c;
  }
  int e0 = off[node], e1 = off[node + 1];
  int e = e0;
  for (; e + 2 <= e1; e += 2) {
    int s0 = csr[e], s1 = csr[e + 1];
    float c0 = coef[e], c1 = coef[e + 1];
    ushort8_v r0 = *(const ushort8_v*)(F + (size_t)s0 * C2 + jq);
    ushort8_v r1 = *(const ushort8_v*)(F + (size_t)s1 * C2 + jq);
    #pragma unroll
    for (int k = 0; k < 8; ++k) acc[k] += us2f(r0[k]) * c0 + us2f(r1[k]) * c1;
  }
  if (e < e1) {
    int s0 = csr[e];
    float c0 = coef[e];
    ushort8_v r0 = *(const ushort8_v*)(F + (size_t)s0 * C2 + jq);
    #pragma unroll
    for (int k = 0; k < 8; ++k) acc[k] += us2f(r0[k]) * c0;
  }
  float* dst = aggX + (size_t)node * C2 + jq;
  *(float4*)(dst)     = make_float4(acc[0], acc[1], acc[2], acc[3]);
  *(float4*)(dst + 4) = make_float4(acc[4], acc[5], acc[6], acc[7]);
}

// ---------------- GEMM: [nodes,K] @ [K,128] -> [nodes,128] ----------------
// MODE 0: out fp32 with bias+relu.  MODE 1: out bf16 raw.
template<int K, int MODE>
__global__ __launch_bounds__(256) void gemm_kernel(const float* __restrict__ A, const float* __restrict__ W,
                                                   const float* __restrict__ bias,
                                                   float* __restrict__ Cf, unsigned short* __restrict__ Cb)
{
  __shared__ float sA[32 * K];
  int tid = threadIdx.x;
  int n0 = blockIdx.x << 5;
  for (int i = tid; i < 32 * K / 4; i += 256)
    ((float4*)sA)[i] = ((const float4*)(A + (size_t)n0 * K))[i];
  __syncthreads();
  int nq = (tid >> 5) << 2;
  int jq = (tid & 31) << 2;
  float acc[4][4] = {};
  #pragma unroll 4
  for (int i4 = 0; i4 < K / 4; ++i4) {
    float wv[4][4];
    #pragma unroll
    for (int ii = 0; ii < 4; ++ii) {
      float4 u = *(const float4*)(&W[(size_t)(i4 * 4 + ii) * HID + jq]);
      wv[ii][0] = u.x; wv[ii][1] = u.y; wv[ii][2] = u.z; wv[ii][3] = u.w;
    }
    #pragma unroll
    for (int nn = 0; nn < 4; ++nn) {
      float4 g = *(const float4*)&sA[(nq + nn) * K + (i4 << 2)];
      #pragma unroll
      for (int jj = 0; jj < 4; ++jj)
        acc[nn][jj] += g.x * wv[0][jj] + g.y * wv[1][jj] + g.z * wv[2][jj] + g.w * wv[3][jj];
    }
  }
  if (MODE == 0) {
    float b0 = bias[jq], b1 = bias[jq + 1], b2 = bias[jq + 2], b3 = bias[jq + 3];
    #pragma unroll
    for (int nn = 0; nn < 4; ++nn) {
      float4 o4 = make_float4(fmaxf(acc[nn][0] + b0, 0.f), fmaxf(acc[nn][1] + b1, 0.f),
                              fmaxf(acc[nn][2] + b2, 0.f), fmaxf(acc[nn][3] + b3, 0.f));
      *(float4*)&Cf[((size_t)(n0 + nq + nn)) * HID + jq] = o4;
    }
  } else {
    #pragma unroll
    for (int nn = 0; nn < 4; ++nn) {
      ushort4 u;
      u.x = f2us(acc[nn][0]);
      u.y = f2us(acc[nn][1]);
      u.z = f2us(acc[nn][2]);
      u.w = f2us(acc[nn][3]);
      *(ushort4*)(Cb + ((size_t)(n0 + nq + nn)) * HID + jq) = u;
    }
  }
}

// ---------------- agg2 + bias + relu + mean-pool (fused) ----------------
// block 256 = 16 nodes x 16 lanes (8 bf16 each); grid 4096; never materializes G2
__global__ __launch_bounds__(256) void agg2_pool_kernel(const unsigned short* __restrict__ Hb, const int* __restrict__ off,
                                                        const int* __restrict__ csr, const float* __restrict__ coef,
                                                        const float* __restrict__ dinv, const float* __restrict__ bias,
                                                        float* __restrict__ pooled)
{
  __shared__ float red[16][HID];           // 8 KB
  int tid = threadIdx.x;
  int g = tid >> 4;                        // local node 0..15
  int jq = (tid & 15) << 3;                // bf16 element offset 0..120
  int node = (blockIdx.x << 4) + g;
  float dn = dinv[node];
  float acc[8];
  {
    ushort8_v r = *(const ushort8_v*)(Hb + (size_t)node * HID + jq);
    float c = dn * dn;
    #pragma unroll
    for (int k = 0; k < 8; ++k) acc[k] = us2f(r[k]) * c;
  }
  int e0 = off[node], e1 = off[node + 1];
  int e = e0;
  for (; e + 2 <= e1; e += 2) {
    int s0 = csr[e], s1 = csr[e + 1];
    float c0 = coef[e], c1 = coef[e + 1];
    ushort8_v r0 = *(const ushort8_v*)(Hb + (size_t)s0 * HID + jq);
    ushort8_v r1 = *(const ushort8_v*)(Hb + (size_t)s1 * HID + jq);
    #pragma unroll
    for (int k = 0; k < 8; ++k) acc[k] += us2f(r0[k]) * c0 + us2f(r1[k]) * c1;
  }
  if (e < e1) {
    int s0 = csr[e];
    float c0 = coef[e];
    ushort8_v r0 = *(const ushort8_v*)(Hb + (size_t)s0 * HID + jq);
    #pragma unroll
    for (int k = 0; k < 8; ++k) acc[k] += us2f(r0[k]) * c0;
  }
  #pragma unroll
  for (int k = 0; k < 8; ++k)
    red[g][jq + k] = fmaxf(acc[k] + bias[jq + k], 0.f);
  __syncthreads();
  if (tid < HID) {
    float s = 0.f;
    #pragma unroll
    for (int g2 = 0; g2 < 16; ++g2) s += red[g2][tid];
    int b = blockIdx.x >> 6;               // 64 blocks per graph
    atomicAdd(&pooled[b * HID + tid], s * (1.0f / 1024.0f));
  }
}

// ---------------- classifier ----------------

__global__ __launch_bounds__(64) void cls_kernel(const float* __restrict__ pooled, const float* __restrict__ w,
                                                 const float* __restrict__ cb, float* __restrict__ out)
{
  int b = blockIdx.x, o = threadIdx.x;
  if (o < OUT_C) {
    float acc = cb[o];
    for (int i = 0; i < HID; ++i)
      acc += pooled[b * HID + i] * w[i * OUT_C + o];
    out[b * OUT_C + o] = acc;
  }
}

// ---------------- launcher ----------------

extern "C" void kernel_launch(void* const* d_in, const int* in_sizes, int n_in,
                              void* d_out, int out_size, void* d_ws, size_t ws_size,
                              hipStream_t stream)
{
  const float* x    = (const float*)d_in[0];
  const int*   ei   = (const int*)d_in[1];
  const float* c1w  = (const float*)d_in[2];
  const float* c1b  = (const float*)d_in[3];
  const float* c2w  = (const float*)d_in[4];
  const float* c2b  = (const float*)d_in[5];
  const float* g1w  = (const float*)d_in[6];
  const float* g1b  = (const float*)d_in[7];
  const float* g2w  = (const float*)d_in[8];
  const float* g2b  = (const float*)d_in[9];
  const float* clsw = (const float*)d_in[10];
  const float* clsb = (const float*)d_in[11];
  float* outp = (float*)d_out;

  char* ws = (char*)d_ws;
  size_t off_b = 0;
  auto alloc = [&](size_t bytes) { void* p = ws + off_b; off_b = (off_b + bytes + 255) & ~(size_t)255; return p; };
  int*   deg    = (int*)  alloc((size_t)N_NODES * 4);
  float* dinvv  = (float*)alloc((size_t)N_NODES * 4);
  int*   offp   = (int*)  alloc((size_t)(N_NODES + 1) * 4);
  int*   cursor = (int*)  alloc((size_t)N_NODES * 4);
  int*   bsum   = (int*)  alloc(256 * 4);
  int*   csr    = (int*)  alloc((size_t)N_EDGES * 4);
  float* coefp  = (float*)alloc((size_t)N_EDGES * 4);
  unsigned short* feats = (unsigned short*)alloc((size_t)N_NODES * C2 * 2);
  float* aggX   = (float*)alloc((size_t)N_NODES * C2 * 4);
  float* G      = (float*)alloc((size_t)N_NODES * HID * 4);
  unsigned short* H = (unsigned short*)alloc((size_t)N_NODES * HID * 2);
  float* pooled = (float*)alloc((size_t)N_B * HID * 4);
  (void)ws_size; (void)in_sizes; (void)n_in; (void)out_size;

  // CSR build
  init_kernel   <<<256, 256, 0, stream>>>(deg, pooled);
  count_kernel  <<<N_EDGES / 256, 256, 0, stream>>>(ei, deg);
  dinv_kernel   <<<N_NODES / 256, 256, 0, stream>>>(deg, dinvv);
  scanA_kernel  <<<256, 256, 0, stream>>>(deg, bsum);
  scanB_kernel  <<<1, 256, 0, stream>>>(bsum);
  scanC_kernel  <<<256, 256, 0, stream>>>(deg, bsum, offp, cursor);
  scatter_kernel<<<N_EDGES / 256, 256, 0, stream>>>(ei, cursor, dinvv, csr, coefp);

  // CNN feature extractor (fused conv1+pool+conv2+pool)
  conv_fused_kernel<<<1024, 256, 0, stream>>>(x, c1w, c1b, c2w, c2b, feats);

  // GCN layer 1: (A X) W1 + b1, relu
  aggX_kernel<<<N_NODES / 64, 256, 0, stream>>>(feats, offp, csr, coefp, dinvv, aggX);
  gemm_kernel<32, 0><<<N_NODES / 32, 256, 0, stream>>>(aggX, g1w, g1b, G, nullptr);

  // GCN layer 2: A (G W2) + b2, relu, fused mean-pool
  gemm_kernel<128, 1><<<N_NODES / 32, 256, 0, stream>>>(G, g2w, nullptr, nullptr, H);
  agg2_pool_kernel<<<N_NODES / 16, 256, 0, stream>>>(H, offp, csr, coefp, dinvv, g2b, pooled);

  // classifier
  cls_kernel<<<N_B, 64, 0, stream>>>(pooled, clsw, clsb, outp);
}